// Round 1
// 318.952 us; speedup vs baseline: 1.0154x; 1.0154x over previous
//
#include <hip/hip_runtime.h>
#include <stdint.h>

// Problem constants (from reference): B,T,X,E,H,L = 4096,32,256,32,512,2
#define B_SZ 4096
#define T_SZ 32
#define X_SZ 256
#define E_SZ 32
#define H_SZ 512
#define BM   64      // batch rows per block
// A-tile LDS row stride: 512 bf16 = 1024B, +16B pad -> conflict-free ds_read_b128
#define AROW 1040

typedef __attribute__((ext_vector_type(8))) short  short8;   // 8 bf16 = 4 VGPR
typedef __attribute__((ext_vector_type(4))) float  floatx4;

// v_cvt_pk_bf16_f32: D[15:0]=bf16(a), D[31:16]=bf16(b), RNE (gfx950 HW instr)
__device__ __forceinline__ unsigned pk2(float a, float b) {
  unsigned r;
  asm("v_cvt_pk_bf16_f32 %0, %1, %2" : "=v"(r) : "v"(a), "v"(b));
  return r;
}

// ---------------------------------------------------------------------------
// Prep v2: fp32 weights -> bf16 MFMA B-fragments via LDS transpose.
// One block per chunk (32 k x 512 n). 1312 chunks total:
//   c in [0,288):    layer-1, c = e*9+kt. kt==0 -> masked W1t rows 0..31;
//                    kt>=1 -> W1x rows (kt-1)*32 .. +31.   out: wcat.
//   c in [288,1312): hidden, c-288 = (layer*32+e)*16 + kt. out: whf.
// Phase 1: each thread loads row-pair (k,k+1) float4 (coalesced 1KB/row/wave),
//   packs pk2(W[k][n],W[k+1][n]) and ds_write_b128 to lds[k2][n] (stride 516
//   u32: 16B-aligned rows, quads split bank halves -> 2-way = free).
// Phase 2: lane gathers k2=4q..4q+3 at its n (4x ds_read_b32, exactly 2
//   lanes/bank = free), stores 16B/lane coalesced fragment units.
// Unit layout (unchanged contract with mlp_kernel): u = nb*64 + l,
//   n = nb*16 + (l&15), local k0 = (l>>4)*8, dword p covers k = k0+2p, k0+2p+1.
// ---------------------------------------------------------------------------
__global__ __launch_bounds__(256) void prep_kernel(
    const float* __restrict__ W1t, const float* __restrict__ W1x,
    const int* __restrict__ masks, const float* __restrict__ Wh,
    uint4* __restrict__ wcat, uint4* __restrict__ whf) {
  __shared__ unsigned lds[16 * 516];           // 33 KB
  const int c = blockIdx.x;
  const int t = threadIdx.x;

  const float* base;                           // row 0 of this chunk's 32 rows
  bool needMask = false;
  int e1 = 0;
  if (c >= 288) {
    int cc = c - 288;
    int le = cc >> 4, kt = cc & 15;            // le = layer*32 + e
    base = Wh + ((size_t)le * H_SZ + kt * 32) * H_SZ;
  } else {
    int e = c / 9, kt = c - e * 9;
    e1 = e;
    if (kt == 0) { base = W1t + (size_t)e * T_SZ * H_SZ; needMask = true; }
    else          base = W1x + ((size_t)e * X_SZ + (kt - 1) * 32) * H_SZ;
  }

#pragma unroll
  for (int i = 0; i < 8; ++i) {
    int g  = i * 256 + t;
    int k2 = g >> 7, np = g & 127;             // k2: wave-uniform
    const float* r0 = base + (size_t)(2 * k2) * H_SZ + np * 4;
    float4 a = *(const float4*)r0;
    float4 b = *(const float4*)(r0 + H_SZ);
    if (needMask) {
      float s0 = (float)masks[e1 * T_SZ + 2 * k2];
      float s1 = (float)masks[e1 * T_SZ + 2 * k2 + 1];
      a.x *= s0; a.y *= s0; a.z *= s0; a.w *= s0;
      b.x *= s1; b.y *= s1; b.z *= s1; b.w *= s1;
    }
    *(uint4*)&lds[k2 * 516 + np * 4] =
        make_uint4(pk2(a.x, b.x), pk2(a.y, b.y), pk2(a.z, b.z), pk2(a.w, b.w));
  }
  __syncthreads();

  uint4* outp = (c < 288) ? (wcat + (size_t)c * 2048)
                          : (whf + (size_t)(c - 288) * 2048);
  const int w = t >> 6, l = t & 63, q = l >> 4, l16 = l & 15;
#pragma unroll
  for (int j = 0; j < 8; ++j) {
    int nb = w * 8 + j;
    int n  = nb * 16 + l16;
    int kb = 4 * q;
    uint4 v;
    v.x = lds[(kb + 0) * 516 + n];
    v.y = lds[(kb + 1) * 516 + n];
    v.z = lds[(kb + 2) * 516 + n];
    v.w = lds[(kb + 3) * 516 + n];
    outp[nb * 64 + l] = v;                     // 16B/lane, lanes consecutive
  }
}

// ---------------------------------------------------------------------------
// Fused MLP: block = (64-row batch tile, expert e). 8 waves; wave w owns
// cols [64w,64w+64). acc 4x4 tiles of mfma_f32_16x16x32_bf16.
// A (activations) in LDS bf16, weights direct-from-global (fragment order).
// Block remap: each XCD (bid&7) owns 4 experts, processed in 64-block
// contiguous runs -> live weight set ~1.3MB << 4MB L2 (kills weight re-fetch).
// ---------------------------------------------------------------------------
__global__ __launch_bounds__(512, 4) void mlp_kernel(
    const float* __restrict__ theta, const float* __restrict__ x,
    const short8* __restrict__ wcat, const short8* __restrict__ whf,
    const float* __restrict__ b1, const float* __restrict__ a1,
    const float* __restrict__ bh, const float* __restrict__ ah,
    const float* __restrict__ Wo, const float* __restrict__ bo,
    float* __restrict__ out) {
  __shared__ __align__(16) char smA[BM * AROW];   // 66560 B (gfx950: 160KB max)
  const int tid = threadIdx.x;
  const int bid = blockIdx.x;
  const int xcd = bid & 7;
  const int t8  = bid >> 3;                       // per-XCD sequence 0..255
  const int e   = xcd * 4 + (t8 >> 6);            // 64 consecutive blocks/expert
  const int m0  = (t8 & 63) * BM;
  const int w   = tid >> 6, l = tid & 63, l16 = l & 15, quad = l >> 4;

  // ---- stage A0 = [theta | x] as bf16 (mask folded into prepped W1t) ----
  {
    int r = tid >> 3, c = tid & 7;                // 8 threads per row
    float4 th = *(const float4*)(theta + (size_t)(m0 + r) * T_SZ + c * 4);
    *(uint2*)(smA + r * AROW + c * 8) = make_uint2(pk2(th.x, th.y), pk2(th.z, th.w));
    const float4* xp = (const float4*)(x + (size_t)(m0 + r) * X_SZ + c * 32);
#pragma unroll
    for (int q = 0; q < 4; ++q) {
      float4 a = xp[q * 2], b = xp[q * 2 + 1];
      *(uint4*)(smA + r * AROW + 64 + c * 64 + q * 16) =
          make_uint4(pk2(a.x, a.y), pk2(a.z, a.w), pk2(b.x, b.y), pk2(b.z, b.w));
    }
  }
  __syncthreads();

  floatx4 acc[4][4];

  // GEMM over nkt K-chunks of 32; B double-buffered from global.
  auto gemm = [&](const short8* wbase, int nkt) {
#pragma unroll
    for (int mb = 0; mb < 4; ++mb)
#pragma unroll
      for (int i = 0; i < 4; ++i) acc[mb][i] = (floatx4)(0.f);
    short8 bcur[4], bnxt[4];
    const int boff = w * 256 + l;
#pragma unroll
    for (int i = 0; i < 4; ++i) bcur[i] = wbase[boff + i * 64];
    for (int kt = 0; kt < nkt; ++kt) {
      const short8* wn = wbase + (size_t)(kt + 1 < nkt ? kt + 1 : kt) * 2048;
#pragma unroll
      for (int i = 0; i < 4; ++i) bnxt[i] = wn[boff + i * 64];
      short8 af[4];
#pragma unroll
      for (int mb = 0; mb < 4; ++mb)
        af[mb] = *(const short8*)(smA + (mb * 16 + l16) * AROW + kt * 64 + quad * 16);
#pragma unroll
      for (int mb = 0; mb < 4; ++mb)
#pragma unroll
        for (int i = 0; i < 4; ++i)
          acc[mb][i] = __builtin_amdgcn_mfma_f32_16x16x32_bf16(af[mb], bcur[i],
                                                               acc[mb][i], 0, 0, 0);
#pragma unroll
      for (int i = 0; i < 4; ++i) bcur[i] = bnxt[i];
    }
  };

  // bias + PReLU + bf16 pair-pack (shfl_xor 1) + write back into A buffer
  auto epi_store = [&](const float* bias, const float* slope) {
    float bb[4], aa[4];
#pragma unroll
    for (int i = 0; i < 4; ++i) {
      int col = w * 64 + i * 16 + l16;
      bb[i] = bias[col];
      aa[i] = slope[col];
    }
    __syncthreads();   // everyone done READING A before we overwrite
#pragma unroll
    for (int mb = 0; mb < 4; ++mb) {
#pragma unroll
      for (int i = 0; i < 4; ++i) {
        unsigned dw[4];
#pragma unroll
        for (int r = 0; r < 4; ++r) {
          float v = acc[mb][i][r] + bb[i];
          v = v >= 0.f ? v : aa[i] * v;
          float o  = __shfl_xor(v, 1, 64);
          float lo = (l16 & 1) ? o : v;
          float hi = (l16 & 1) ? v : o;
          dw[r] = pk2(lo, hi);
        }
        int col2  = w * 64 + i * 16 + (l16 & ~1);
        int rbase = (l16 & 1) * 2;                 // even lanes rows 0,1; odd 2,3
#pragma unroll
        for (int rr = 0; rr < 2; ++rr) {
          int row = mb * 16 + quad * 4 + rbase + rr;
          *(unsigned*)(smA + row * AROW + col2 * 2) = dw[rbase + rr];
        }
      }
    }
    __syncthreads();
  };

  // ---- layer 1: K = 288 (9 chunks) ----
  gemm(wcat + (size_t)e * 9 * 2048, 9);
  epi_store(b1 + (size_t)e * H_SZ, a1 + (size_t)e * H_SZ);
  // ---- hidden layer 0: K = 512 (16 chunks) ----
  gemm(whf + (size_t)e * 16 * 2048, 16);
  epi_store(bh + (size_t)e * H_SZ, ah + (size_t)e * H_SZ);
  // ---- hidden layer 1 + fused output dot (fp32, no bf16 rounding) ----
  gemm(whf + (size_t)(E_SZ + e) * 16 * 2048, 16);
  {
    float bb[4], aa[4], wo[4];
#pragma unroll
    for (int i = 0; i < 4; ++i) {
      int col = w * 64 + i * 16 + l16;
      bb[i] = bh[(size_t)(E_SZ + e) * H_SZ + col];
      aa[i] = ah[(size_t)(E_SZ + e) * H_SZ + col];
      wo[i] = Wo[(size_t)e * H_SZ + col];
    }
    float ps[4][4];
#pragma unroll
    for (int mb = 0; mb < 4; ++mb)
#pragma unroll
      for (int r = 0; r < 4; ++r) ps[mb][r] = 0.f;
#pragma unroll
    for (int mb = 0; mb < 4; ++mb)
#pragma unroll
      for (int i = 0; i < 4; ++i)
#pragma unroll
        for (int r = 0; r < 4; ++r) {
          float v = acc[mb][i][r] + bb[i];
          v = v >= 0.f ? v : aa[i] * v;
          ps[mb][r] += v * wo[i];
        }
    // reduce over the 16 lanes of each quad (cols within this wave's slice)
#pragma unroll
    for (int d = 1; d < 16; d <<= 1)
#pragma unroll
      for (int mb = 0; mb < 4; ++mb)
#pragma unroll
        for (int r = 0; r < 4; ++r) ps[mb][r] += __shfl_xor(ps[mb][r], d, 64);
    __syncthreads();                 // done reading A; reuse its storage
    float* scratch = (float*)smA;    // [64 rows][8 waves]
    if (l16 == 0) {
#pragma unroll
      for (int mb = 0; mb < 4; ++mb)
#pragma unroll
        for (int r = 0; r < 4; ++r)
          scratch[(mb * 16 + quad * 4 + r) * 8 + w] = ps[mb][r];
    }
    __syncthreads();
    if (tid < BM) {
      float s = 0.f;
#pragma unroll
      for (int ww = 0; ww < 8; ++ww) s += scratch[tid * 8 + ww];
      out[(size_t)(m0 + tid) * E_SZ + e] = s + bo[e];
    }
  }
}

// ---------------------------------------------------------------------------
extern "C" void kernel_launch(void* const* d_in, const int* in_sizes, int n_in,
                              void* d_out, int out_size, void* d_ws, size_t ws_size,
                              hipStream_t stream) {
  const float* theta = (const float*)d_in[0];
  const float* x     = (const float*)d_in[1];
  const int*   masks = (const int*)d_in[2];
  const float* W1t   = (const float*)d_in[3];
  const float* W1x   = (const float*)d_in[4];
  const float* b1    = (const float*)d_in[5];
  const float* a1    = (const float*)d_in[6];
  const float* Wh    = (const float*)d_in[7];
  const float* bh    = (const float*)d_in[8];
  const float* ah    = (const float*)d_in[9];
  const float* Wo    = (const float*)d_in[10];
  const float* bo    = (const float*)d_in[11];
  float* out = (float*)d_out;

  // ws layout: [0, 9.4MB) layer-1 frags; [9.4MB, 43MB) hidden frags.
  uint4* wcat = (uint4*)d_ws;
  uint4* whf  = (uint4*)((char*)d_ws + (size_t)E_SZ * 9 * 2048 * 16);

  // 288 layer-1 chunks + 1024 hidden chunks, one block each
  prep_kernel<<<1312, 256, 0, stream>>>(W1t, W1x, masks, Wh, wcat, whf);
  mlp_kernel<<<2048, 512, 0, stream>>>(theta, x, (const short8*)wcat,
                                       (const short8*)whf, b1, a1, bh, ah, Wo, bo,
                                       out);
}